// Round 1
// baseline (124.662 us; speedup 1.0000x reference)
//
#include <hip/hip_runtime.h>
#include <stdint.h>

#define EPS 1e-5f
#define N_NODES 8192

typedef __attribute__((ext_vector_type(8))) short short8;
typedef __attribute__((ext_vector_type(4))) float floatx4;

__device__ __forceinline__ short f2bf(float f) {
    uint32_t u = __float_as_uint(f);
    u += 0x7FFFu + ((u >> 16) & 1u);
    return (short)(u >> 16);
}
__device__ __forceinline__ float bf2f(short s) {
    return __uint_as_float(((uint32_t)(uint16_t)s) << 16);
}

// ---------------- y = x @ W1 (bf16 MFMA, fp32 accumulate/out) ----------------
// block = 256 (4 waves), each wave does a 16-row stripe across all 128 cols.
__global__ __launch_bounds__(256) void gemm_y_kernel(
    const float* __restrict__ x, const float* __restrict__ W1,
    float* __restrict__ y)
{
    const int wv   = threadIdx.x >> 6;
    const int lane = threadIdx.x & 63;
    const int ml   = lane & 15;
    const int q    = lane >> 4;
    const int rb   = blockIdx.x * 64 + wv * 16;

    // A fragments for 4 k-chunks: A[m=lane&15][k = 32c + 8q + j]
    short8 afrag[4];
    const float* arow = x + (rb + ml) * 128;
#pragma unroll
    for (int c = 0; c < 4; ++c) {
        const float* ap = arow + c * 32 + q * 8;
        floatx4 lo = *(const floatx4*)ap;
        floatx4 hi = *(const floatx4*)(ap + 4);
        short8 a;
        a[0] = f2bf(lo[0]); a[1] = f2bf(lo[1]); a[2] = f2bf(lo[2]); a[3] = f2bf(lo[3]);
        a[4] = f2bf(hi[0]); a[5] = f2bf(hi[1]); a[6] = f2bf(hi[2]); a[7] = f2bf(hi[3]);
        afrag[c] = a;
    }
#pragma unroll
    for (int nt = 0; nt < 8; ++nt) {
        floatx4 acc = {0.f, 0.f, 0.f, 0.f};
        const int ncol = nt * 16 + ml;
#pragma unroll
        for (int c = 0; c < 4; ++c) {
            const int kb = c * 32 + q * 8;
            short8 b;   // B[k = kb + j][n = ncol]
#pragma unroll
            for (int j = 0; j < 8; ++j) b[j] = f2bf(W1[(kb + j) * 128 + ncol]);
            acc = __builtin_amdgcn_mfma_f32_16x16x32_bf16(afrag[c], b, acc, 0, 0, 0);
        }
        // D: row = 4q + r, col = ml   (m89-verified layout)
#pragma unroll
        for (int r = 0; r < 4; ++r)
            y[(rb + q * 4 + r) * 128 + ncol] = acc[r];
    }
}

// ---------------- main per-cloud all-pairs kernel ----------------
// grid = 512: s = bx>>6 (split 0..7), c = bx&63 (cloud) -> cloud's 8 splits share bx%8 (XCD).
// block = 256: d = tid&127, g = tid>>7; group g handles 8 i's (register tiled).
__global__ __launch_bounds__(256) void cloud_main_kernel(
    const float* __restrict__ x, const float* __restrict__ xyz,
    const float* __restrict__ W_xyz, const float* __restrict__ b1,
    const float* __restrict__ ln_gamma, const float* __restrict__ ln_beta,
    const float* __restrict__ y_ws, float* __restrict__ p2_ws,
    float* __restrict__ stat_ws, float* __restrict__ out)
{
    __shared__ float smem[10784];
    short* s_z16 = (short*)smem;            // z tile bf16 [128][128], 32 KB
    float* s_w   = smem + 8192;             // w_t[j][16] fp32, 8 KB
    float* s_xyz = smem + 10240;            // [128][4]
    float* s_mu  = smem + 10752;            // [16]
    float* s_rs  = smem + 10768;            // [16]
    float* s_p1  = smem;                    // alias z region after loop: [16][132]
    float* s_bn  = smem + 8192;             // alias w region after loop: [4][128]

    const int bx  = blockIdx.x;
    const int c   = bx & 63;
    const int s   = bx >> 6;
    const int tid = threadIdx.x;
    const int d   = tid & 127;
    const int g   = tid >> 7;
    const int node0 = c * 128;

    // phase 0: stage xyz
    if (tid < 128) {
        const float* p = xyz + (node0 + tid) * 3;
        s_xyz[tid * 4 + 0] = p[0];
        s_xyz[tid * 4 + 1] = p[1];
        s_xyz[tid * 4 + 2] = p[2];
    }
    __syncthreads();

    // phase 1: z tile (bf16): z[j][d] = xyz_j . W_xyz[:,d]
    {
        float w0 = W_xyz[d], w1 = W_xyz[128 + d], w2 = W_xyz[256 + d];
        for (int jj = 0; jj < 64; ++jj) {
            int j = g * 64 + jj;
            float zv = s_xyz[j * 4] * w0 + s_xyz[j * 4 + 1] * w1 + s_xyz[j * 4 + 2] * w2;
            s_z16[j * 128 + d] = f2bf(zv);
        }
    }
    // phase 2: w tile for this block's 16 i's x 128 j  (self pair -> w=1, handled later)
    {
        const int i0 = s * 16;
        for (int e = tid; e < 2048; e += 256) {
            int j = e >> 4, ii = e & 15, ia = i0 + ii;
            float dx = s_xyz[ia * 4]     - s_xyz[j * 4];
            float dy = s_xyz[ia * 4 + 1] - s_xyz[j * 4 + 1];
            float dz = s_xyz[ia * 4 + 2] - s_xyz[j * 4 + 2];
            float dist = sqrtf(dx * dx + dy * dy + dz * dz);
            s_w[j * 16 + ii] = __expf(-dist);
        }
    }
    __syncthreads();

    // phase 3: all-pairs accumulation (VALU-bound core)
    const int iL0 = s * 16 + g * 8;
    float yi[8], zi[8], acc1[8], acc2[8];
    const float b1d = b1[d];
#pragma unroll
    for (int r = 0; r < 8; ++r) {
        yi[r] = y_ws[(node0 + iL0 + r) * 128 + d];
        zi[r] = bf2f(s_z16[(iL0 + r) * 128 + d]);
        acc1[r] = 0.f; acc2[r] = 0.f;
    }
    const float* yrow = y_ws + node0 * 128 + d;
#pragma unroll 2
    for (int j = 0; j < 128; ++j) {
        float yj = yrow[j * 128];
        float zj = bf2f(s_z16[j * 128 + d]);
        floatx4 w0 = *(const floatx4*)(s_w + j * 16 + g * 8);
        floatx4 w1 = *(const floatx4*)(s_w + j * 16 + g * 8 + 4);
#pragma unroll
        for (int r = 0; r < 8; ++r) {
            float w = (r < 4) ? w0[r] : w1[r - 4];
            float t1 = w * (yi[r] - yj) + b1d;
            acc1[r] += fmaxf(t1, 0.f);
            float t2 = zi[r] - zj;
            acc2[r] += fmaxf(t2, 0.f);
        }
    }
    // remove self term of p1: w=1, diff=0 -> relu(b1d). (p2 self term is exactly 0.)
#pragma unroll
    for (int r = 0; r < 8; ++r) acc1[r] -= fmaxf(b1d, 0.f);

    __syncthreads();   // all z/w reads done; safe to alias LDS

    // phase 4: stash p1 for LN reduce; BN partials per group
    {
        float bs = 0.f, bq = 0.f;
#pragma unroll
        for (int r = 0; r < 8; ++r) {
            s_p1[(g * 8 + r) * 132 + d] = acc1[r];
            bs += acc2[r];
            bq += acc2[r] * acc2[r];
        }
        s_bn[g * 128 + d]       = bs;
        s_bn[256 + g * 128 + d] = bq;
    }
    __syncthreads();

    // LN stats: 16 threads per i, each sums 8 d's, then 16-lane shuffle reduce
    {
        int ii = tid >> 4, sub = tid & 15;
        float ps = 0.f, pq = 0.f;
#pragma unroll
        for (int e = 0; e < 8; ++e) {
            float v = s_p1[ii * 132 + sub * 8 + e];
            ps += v; pq += v * v;
        }
#pragma unroll
        for (int m = 1; m < 16; m <<= 1) {
            ps += __shfl_xor(ps, m, 64);
            pq += __shfl_xor(pq, m, 64);
        }
        if (sub == 0) {
            float mu  = ps * (1.f / 128.f);
            float var = pq * (1.f / 128.f) - mu * mu;
            s_mu[ii] = mu;
            s_rs[ii] = rsqrtf(var + EPS);
        }
    }
    // BN global partial sums (one atomic per d per counter per block)
    if (tid < 128) {
        atomicAdd(stat_ws + tid,       s_bn[tid] + s_bn[128 + tid]);
        atomicAdd(stat_ws + 128 + tid, s_bn[256 + tid] + s_bn[384 + tid]);
    }
    __syncthreads();

    // phase 5: out = x + LN(p1)*lng + lnb ; store p2
    const float lng = ln_gamma[d], lnb = ln_beta[d];
#pragma unroll
    for (int r = 0; r < 8; ++r) {
        int ii = g * 8 + r;
        int gi = node0 + iL0 + r;
        float o = x[gi * 128 + d] + (acc1[r] - s_mu[ii]) * s_rs[ii] * lng + lnb;
        out[gi * 128 + d]   = o;
        p2_ws[gi * 128 + d] = acc2[r];
    }
}

// ---------------- finalize: out += BN(p2) ----------------
__global__ __launch_bounds__(256) void finalize_kernel(
    const float* __restrict__ p2_ws, const float* __restrict__ stat_ws,
    const float* __restrict__ bn_gamma, const float* __restrict__ bn_beta,
    float* __restrict__ out)
{
    int t = blockIdx.x * 256 + threadIdx.x;   // over N*D/4
    int base = t * 4;
    int d0 = base & 127;
    floatx4 p2 = *(const floatx4*)(p2_ws + base);
    floatx4 o  = *(const floatx4*)(out + base);
#pragma unroll
    for (int e = 0; e < 4; ++e) {
        int dd = d0 + e;
        float mu  = stat_ws[dd] * (1.f / 8192.f);
        float var = stat_ws[128 + dd] * (1.f / 8192.f) - mu * mu;
        float rs  = rsqrtf(var + EPS);
        o[e] += (p2[e] - mu) * rs * bn_gamma[dd] + bn_beta[dd];
    }
    *(floatx4*)(out + base) = o;
}

extern "C" void kernel_launch(void* const* d_in, const int* in_sizes, int n_in,
                              void* d_out, int out_size, void* d_ws, size_t ws_size,
                              hipStream_t stream) {
    const float* x        = (const float*)d_in[0];
    const float* xyz      = (const float*)d_in[1];
    const float* W_xyz    = (const float*)d_in[2];
    const float* bn_gamma = (const float*)d_in[3];
    const float* bn_beta  = (const float*)d_in[4];
    const float* W1       = (const float*)d_in[5];
    const float* b1       = (const float*)d_in[6];
    const float* ln_gamma = (const float*)d_in[7];
    const float* ln_beta  = (const float*)d_in[8];
    float* out = (float*)d_out;

    float* y_ws    = (float*)d_ws;                 // [8192][128] fp32
    float* p2_ws   = y_ws + N_NODES * 128;         // [8192][128] fp32
    float* stat_ws = p2_ws + N_NODES * 128;        // sum[128], sumsq[128]

    hipMemsetAsync(stat_ws, 0, 256 * sizeof(float), stream);
    gemm_y_kernel<<<128, 256, 0, stream>>>(x, W1, y_ws);
    cloud_main_kernel<<<512, 256, 0, stream>>>(x, xyz, W_xyz, b1, ln_gamma, ln_beta,
                                               y_ws, p2_ws, stat_ws, out);
    finalize_kernel<<<1024, 256, 0, stream>>>(p2_ws, stat_ws, bn_gamma, bn_beta, out);
}

// Round 2
// 118.268 us; speedup vs baseline: 1.0541x; 1.0541x over previous
//
#include <hip/hip_runtime.h>
#include <stdint.h>

#define EPS 1e-5f
#define N_NODES 8192

typedef __attribute__((ext_vector_type(8))) short short8;
typedef __attribute__((ext_vector_type(4))) float floatx4;
typedef __attribute__((ext_vector_type(2))) float floatx2;
typedef __attribute__((ext_vector_type(4))) unsigned short ushortx4;

__device__ __forceinline__ unsigned short f2bf(float f) {
    uint32_t u = __float_as_uint(f);
    u += 0x7FFFu + ((u >> 16) & 1u);
    return (unsigned short)(u >> 16);
}

// ---------------- prep: x -> bf16 (row-major), W1 -> bf16 transposed, zero BN stats ----
// blocks 0..1023: convert x (4 elems/thread, vectorized). blocks 1024..1039: W1^T (+stats zero).
__global__ __launch_bounds__(256) void prep_kernel(
    const float* __restrict__ x, const float* __restrict__ W1,
    unsigned short* __restrict__ xb, unsigned short* __restrict__ w1t,
    float* __restrict__ stat_ws)
{
    const int bx = blockIdx.x, tid = threadIdx.x;
    if (bx < 1024) {
        const int base = bx * 1024 + tid * 4;
        floatx4 v = *(const floatx4*)(x + base);
        ushortx4 o = { f2bf(v[0]), f2bf(v[1]), f2bf(v[2]), f2bf(v[3]) };
        *(ushortx4*)(xb + base) = o;
    } else {
        const int b2 = bx - 1024;             // 0..15
        const int n = b2 * 8 + (tid >> 5);    // 0..127
        const int k = (tid & 31) * 4;
#pragma unroll
        for (int e = 0; e < 4; ++e)
            w1t[n * 128 + k + e] = f2bf(W1[(k + e) * 128 + n]);
        if (b2 == 0) {                        // zero 4 banks x 256 stats
            floatx4 z = {0.f, 0.f, 0.f, 0.f};
            *(floatx4*)(stat_ws + tid * 4) = z;
        }
    }
}

// ---------------- y = x @ W1 (bf16 MFMA, fp32 out). 512 blocks x 1 wave x 16 rows ----
__global__ __launch_bounds__(64) void gemm_y_kernel(
    const unsigned short* __restrict__ xb, const unsigned short* __restrict__ w1t,
    float* __restrict__ y)
{
    const int lane = threadIdx.x;
    const int ml = lane & 15, q = lane >> 4;
    const int rb = blockIdx.x * 16;

    short8 afrag[4];    // A[m=ml][k=32c+8q+j]
#pragma unroll
    for (int c = 0; c < 4; ++c)
        afrag[c] = *(const short8*)(xb + (rb + ml) * 128 + c * 32 + q * 8);

#pragma unroll
    for (int nt = 0; nt < 8; ++nt) {
        floatx4 acc = {0.f, 0.f, 0.f, 0.f};
        const int ncol = nt * 16 + ml;
#pragma unroll
        for (int c = 0; c < 4; ++c) {
            // B[k=32c+8q+j][n=ncol] = W1T[ncol][32c+8q+j], contiguous -> 16B load
            short8 b = *(const short8*)(w1t + ncol * 128 + c * 32 + q * 8);
            acc = __builtin_amdgcn_mfma_f32_16x16x32_bf16(afrag[c], b, acc, 0, 0, 0);
        }
#pragma unroll
        for (int r = 0; r < 4; ++r)
            y[(rb + q * 4 + r) * 128 + ncol] = acc[r];   // D: row=4q+r, col=ml (m89)
    }
}

// ---------------- main all-pairs kernel ----------------
// grid = 1024: c = bx&63 (cloud), s = bx>>6 (split 0..15); 8 i's per block.
// block = 256: d = tid&127, g = tid>>7; each group handles 4 i's (register tiled).
__global__ __launch_bounds__(256, 4) void cloud_main_kernel(
    const float* __restrict__ x, const float* __restrict__ xyz,
    const float* __restrict__ W_xyz, const float* __restrict__ b1,
    const float* __restrict__ ln_gamma, const float* __restrict__ ln_beta,
    const float* __restrict__ y_ws, float* __restrict__ p2_ws,
    float* __restrict__ stat_ws, float* __restrict__ out)
{
    __shared__ float smem[1616];
    float* s_w   = smem;              // [128 j][8 i], 4 KB   (live: prologue..loop)
    float* s_xyz = smem + 1024;       // [128][4], 2 KB       (live: prologue..loop)
    float* s_p1  = smem;              // alias [8][136]       (live: after loop)
    float* s_bn  = smem + 1088;       // [2 g][2 stat][128 d] (live: after loop)
    float* s_mu  = smem + 1600;       // [8]
    float* s_rs  = smem + 1608;       // [8]

    const int bx = blockIdx.x;
    const int c = bx & 63, s = bx >> 6;
    const int tid = threadIdx.x;
    const int d = tid & 127, g = tid >> 7;
    const int node0 = c * 128;
    const int i0 = s * 8;
    const int iL0 = i0 + g * 4;

    // stage xyz as float4
    if (tid < 128) {
        const float* p = xyz + (node0 + tid) * 3;
        s_xyz[tid * 4 + 0] = p[0];
        s_xyz[tid * 4 + 1] = p[1];
        s_xyz[tid * 4 + 2] = p[2];
        s_xyz[tid * 4 + 3] = 0.f;
    }
    __syncthreads();

    // w tile: w[j][ii] = exp(-|xyz_i - xyz_j|) for this block's 8 i's
    for (int e = tid; e < 1024; e += 256) {
        const int j = e >> 3, ii = e & 7, ia = i0 + ii;
        float dx = s_xyz[ia * 4]     - s_xyz[j * 4];
        float dy = s_xyz[ia * 4 + 1] - s_xyz[j * 4 + 1];
        float dz = s_xyz[ia * 4 + 2] - s_xyz[j * 4 + 2];
        s_w[j * 8 + ii] = __expf(-sqrtf(dx * dx + dy * dy + dz * dz));
    }
    __syncthreads();

    const float w0 = W_xyz[d], w1c = W_xyz[128 + d], w2c = W_xyz[256 + d];
    const float b1d = b1[d];

    floatx2 yi[2], zi[2], a1[2], a2[2];
#pragma unroll
    for (int r = 0; r < 4; ++r) {
        const int ia = iL0 + r;
        yi[r >> 1][r & 1] = y_ws[(node0 + ia) * 128 + d];
        zi[r >> 1][r & 1] = s_xyz[ia * 4] * w0 + s_xyz[ia * 4 + 1] * w1c
                          + s_xyz[ia * 4 + 2] * w2c;
        a1[r >> 1][r & 1] = 0.f;
        a2[r >> 1][r & 1] = 0.f;
    }
    const floatx2 b1v = {b1d, b1d};
    const floatx2 zv2 = {0.f, 0.f};
    const float* yrow = y_ws + node0 * 128 + d;

#pragma unroll 4
    for (int j = 0; j < 128; ++j) {
        const float yj = yrow[j * 128];
        floatx4 xj = *(const floatx4*)(s_xyz + j * 4);      // broadcast
        const float zj = xj[0] * w0 + xj[1] * w1c + xj[2] * w2c;
        floatx4 wv = *(const floatx4*)(s_w + j * 8 + g * 4); // broadcast
        floatx2 wlo = {wv[0], wv[1]}, whi = {wv[2], wv[3]};
        floatx2 yj2 = {yj, yj}, zj2 = {zj, zj};
        floatx2 t0 = wlo * (yi[0] - yj2) + b1v;
        floatx2 t1 = whi * (yi[1] - yj2) + b1v;
        a1[0] += __builtin_elementwise_max(t0, zv2);
        a1[1] += __builtin_elementwise_max(t1, zv2);
        a2[0] += __builtin_elementwise_max(zi[0] - zj2, zv2);
        a2[1] += __builtin_elementwise_max(zi[1] - zj2, zv2);
    }
    // remove p1 self term: w=1, diff=0 -> relu(b1d). p2 self term is exactly 0.
    {
        const float sc = fmaxf(b1d, 0.f);
        floatx2 scv = {sc, sc};
        a1[0] -= scv; a1[1] -= scv;
    }
    __syncthreads();   // s_w / s_xyz dead; alias LDS

    // stash p1 for LN reduce; per-group BN partials
    {
        float bs = 0.f, bq = 0.f;
#pragma unroll
        for (int r = 0; r < 4; ++r) {
            s_p1[(g * 4 + r) * 136 + d] = a1[r >> 1][r & 1];
            float v2 = a2[r >> 1][r & 1];
            bs += v2;
            bq += v2 * v2;
        }
        s_bn[g * 256 + d] = bs;
        s_bn[g * 256 + 128 + d] = bq;
    }
    __syncthreads();

    // LN stats: 32 threads per i, 4 d's each, shuffle reduce
    {
        const int ii = tid >> 5, sub = tid & 31;
        floatx4 v = *(const floatx4*)(s_p1 + ii * 136 + sub * 4);
        float ps = v[0] + v[1] + v[2] + v[3];
        float pq = v[0] * v[0] + v[1] * v[1] + v[2] * v[2] + v[3] * v[3];
#pragma unroll
        for (int m = 1; m < 32; m <<= 1) {
            ps += __shfl_xor(ps, m, 64);
            pq += __shfl_xor(pq, m, 64);
        }
        if (sub == 0) {
            float mu = ps * (1.f / 128.f);
            float var = pq * (1.f / 128.f) - mu * mu;
            s_mu[ii] = mu;
            s_rs[ii] = rsqrtf(var + EPS);
        }
    }
    // BN partials -> 4 atomic banks (contention: 256 adds/address)
    if (tid < 128) {
        const int bank = (s & 3) * 256;
        atomicAdd(stat_ws + bank + d,       s_bn[d] + s_bn[256 + d]);
        atomicAdd(stat_ws + bank + 128 + d, s_bn[128 + d] + s_bn[384 + d]);
    }
    __syncthreads();

    // epilogue: out = x + LN(p1)*lng + lnb ; store p2
    const float lng = ln_gamma[d], lnb = ln_beta[d];
#pragma unroll
    for (int r = 0; r < 4; ++r) {
        const int ii = g * 4 + r;
        const int gi = node0 + iL0 + r;
        float o = x[gi * 128 + d] + (a1[r >> 1][r & 1] - s_mu[ii]) * s_rs[ii] * lng + lnb;
        out[gi * 128 + d] = o;
        p2_ws[gi * 128 + d] = a2[r >> 1][r & 1];
    }
}

// ---------------- finalize: out += BN(p2) ----------------
__global__ __launch_bounds__(256) void finalize_kernel(
    const float* __restrict__ p2_ws, const float* __restrict__ stat_ws,
    const float* __restrict__ bn_gamma, const float* __restrict__ bn_beta,
    float* __restrict__ out)
{
    __shared__ float sA[128], sB[128];
    const int tid = threadIdx.x;
    if (tid < 128) {
        float sm = 0.f, sq = 0.f;
#pragma unroll
        for (int b = 0; b < 4; ++b) {
            sm += stat_ws[b * 256 + tid];
            sq += stat_ws[b * 256 + 128 + tid];
        }
        float mu = sm * (1.f / 8192.f);
        float var = sq * (1.f / 8192.f) - mu * mu;
        float rs = rsqrtf(var + EPS);
        float A = rs * bn_gamma[tid];
        sA[tid] = A;
        sB[tid] = bn_beta[tid] - mu * A;
    }
    __syncthreads();
    const int base = (blockIdx.x * 256 + tid) * 4;
    const int d0 = base & 127;
    floatx4 p2 = *(const floatx4*)(p2_ws + base);
    floatx4 o  = *(const floatx4*)(out + base);
#pragma unroll
    for (int e = 0; e < 4; ++e)
        o[e] += p2[e] * sA[d0 + e] + sB[d0 + e];
    *(floatx4*)(out + base) = o;
}

extern "C" void kernel_launch(void* const* d_in, const int* in_sizes, int n_in,
                              void* d_out, int out_size, void* d_ws, size_t ws_size,
                              hipStream_t stream) {
    const float* x        = (const float*)d_in[0];
    const float* xyz      = (const float*)d_in[1];
    const float* W_xyz    = (const float*)d_in[2];
    const float* bn_gamma = (const float*)d_in[3];
    const float* bn_beta  = (const float*)d_in[4];
    const float* W1       = (const float*)d_in[5];
    const float* b1       = (const float*)d_in[6];
    const float* ln_gamma = (const float*)d_in[7];
    const float* ln_beta  = (const float*)d_in[8];
    float* out = (float*)d_out;

    float* y_ws    = (float*)d_ws;                       // [8192][128] fp32, 4 MB
    float* p2_ws   = y_ws + N_NODES * 128;               // [8192][128] fp32, 4 MB
    float* stat_ws = p2_ws + N_NODES * 128;              // 4 banks x (sum[128], sumsq[128])
    unsigned short* xb  = (unsigned short*)(stat_ws + 1024);  // [8192][128] bf16, 2 MB
    unsigned short* w1t = xb + N_NODES * 128;                 // [128][128] bf16 (transposed)

    prep_kernel<<<1040, 256, 0, stream>>>(x, W1, xb, w1t, stat_ws);
    gemm_y_kernel<<<512, 64, 0, stream>>>(xb, w1t, y_ws);
    cloud_main_kernel<<<1024, 256, 0, stream>>>(x, xyz, W_xyz, b1, ln_gamma, ln_beta,
                                                y_ws, p2_ws, stat_ws, out);
    finalize_kernel<<<1024, 256, 0, stream>>>(p2_ws, stat_ws, bn_gamma, bn_beta, out);
}

// Round 3
// 113.044 us; speedup vs baseline: 1.1028x; 1.0462x over previous
//
#include <hip/hip_runtime.h>
#include <stdint.h>

#define EPS 1e-5f
#define N_NODES 8192

typedef __attribute__((ext_vector_type(8))) short short8;
typedef __attribute__((ext_vector_type(4))) float floatx4;
typedef __attribute__((ext_vector_type(2))) float floatx2;
typedef __attribute__((ext_vector_type(4))) unsigned short ushortx4;

__device__ __forceinline__ unsigned short f2bf(float f) {
    uint32_t u = __float_as_uint(f);
    u += 0x7FFFu + ((u >> 16) & 1u);
    return (unsigned short)(u >> 16);
}

// ---------------- prep: x -> bf16 (row-major), W1 -> bf16 transposed, zero BN stats ----
__global__ __launch_bounds__(256) void prep_kernel(
    const float* __restrict__ x, const float* __restrict__ W1,
    unsigned short* __restrict__ xb, unsigned short* __restrict__ w1t,
    float* __restrict__ stat_ws)
{
    const int bx = blockIdx.x, tid = threadIdx.x;
    if (bx < 1024) {
        const int base = bx * 1024 + tid * 4;
        floatx4 v = *(const floatx4*)(x + base);
        ushortx4 o = { f2bf(v[0]), f2bf(v[1]), f2bf(v[2]), f2bf(v[3]) };
        *(ushortx4*)(xb + base) = o;
    } else {
        const int b2 = bx - 1024;             // 0..15
        const int n = b2 * 8 + (tid >> 5);    // 0..127
        const int k = (tid & 31) * 4;
#pragma unroll
        for (int e = 0; e < 4; ++e)
            w1t[n * 128 + k + e] = f2bf(W1[(k + e) * 128 + n]);
        if (b2 == 0) {
            floatx4 z = {0.f, 0.f, 0.f, 0.f};
            *(floatx4*)(stat_ws + tid * 4) = z;
        }
    }
}

// ---------------- y = x @ W1 (bf16 MFMA, fp32 out). 512 blocks x 1 wave x 16 rows ----
__global__ __launch_bounds__(64) void gemm_y_kernel(
    const unsigned short* __restrict__ xb, const unsigned short* __restrict__ w1t,
    float* __restrict__ y)
{
    const int lane = threadIdx.x;
    const int ml = lane & 15, q = lane >> 4;
    const int rb = blockIdx.x * 16;

    short8 afrag[4];    // A[m=ml][k=32c+8q+j]
#pragma unroll
    for (int c = 0; c < 4; ++c)
        afrag[c] = *(const short8*)(xb + (rb + ml) * 128 + c * 32 + q * 8);

#pragma unroll
    for (int nt = 0; nt < 8; ++nt) {
        floatx4 acc = {0.f, 0.f, 0.f, 0.f};
        const int ncol = nt * 16 + ml;
#pragma unroll
        for (int c = 0; c < 4; ++c) {
            short8 b = *(const short8*)(w1t + ncol * 128 + c * 32 + q * 8);
            acc = __builtin_amdgcn_mfma_f32_16x16x32_bf16(afrag[c], b, acc, 0, 0, 0);
        }
#pragma unroll
        for (int r = 0; r < 4; ++r)
            y[(rb + q * 4 + r) * 128 + ncol] = acc[r];   // D: row=4q+r, col=ml (m89)
    }
}

// ---------------- main all-pairs kernel ----------------
// grid = 1024: c = bx&63 (cloud), s = bx>>6 (split 0..15); 8 i's per block.
// block = 256: d = tid&127, h = tid>>7 (j-half). Every thread handles 8 i's
// over its 64-j half; halves merge through LDS after the loop.
__global__ __launch_bounds__(256, 4) void cloud_main_kernel(
    const float* __restrict__ x, const float* __restrict__ xyz,
    const float* __restrict__ W_xyz, const float* __restrict__ b1,
    const float* __restrict__ ln_gamma, const float* __restrict__ ln_beta,
    const float* __restrict__ y_ws, float* __restrict__ p2_ws,
    float* __restrict__ stat_ws, float* __restrict__ out)
{
    __shared__ float s_xyz[512];    // [128][4]
    __shared__ float s_w[1024];     // [128 j][8 i]
    __shared__ float s_red[2048];   // h=1 partials: a1[8][128], a2[8][128]
    __shared__ float s_p1[1088];    // [8][136] merged p1 for LN reduce
    __shared__ float s_bn[256];     // BN partials per d
    __shared__ float s_mu[8];
    __shared__ float s_rs[8];

    const int bx = blockIdx.x;
    const int c = bx & 63, s = bx >> 6;
    const int tid = threadIdx.x;
    const int d = tid & 127, h = tid >> 7;
    const int node0 = c * 128;
    const int i0 = s * 8;

    // stage xyz as float4
    if (tid < 128) {
        const float* p = xyz + (node0 + tid) * 3;
        s_xyz[tid * 4 + 0] = p[0];
        s_xyz[tid * 4 + 1] = p[1];
        s_xyz[tid * 4 + 2] = p[2];
        s_xyz[tid * 4 + 3] = 0.f;
    }
    __syncthreads();

    // w tile: w[j][ii] = exp(-|xyz_{i0+ii} - xyz_j|)
    for (int e = tid; e < 1024; e += 256) {
        const int j = e >> 3, ii = e & 7, ia = i0 + ii;
        float dx = s_xyz[ia * 4]     - s_xyz[j * 4];
        float dy = s_xyz[ia * 4 + 1] - s_xyz[j * 4 + 1];
        float dz = s_xyz[ia * 4 + 2] - s_xyz[j * 4 + 2];
        s_w[j * 8 + ii] = __expf(-sqrtf(dx * dx + dy * dy + dz * dz));
    }
    __syncthreads();

    const float w0 = W_xyz[d], w1c = W_xyz[128 + d], w2c = W_xyz[256 + d];
    const float b1d = b1[d];
    const floatx2 b1v = {b1d, b1d};
    const floatx2 zv2 = {0.f, 0.f};

    floatx2 yi[4], zi[4], a1[4], a2[4];
#pragma unroll
    for (int r = 0; r < 8; ++r) {
        const int ia = i0 + r;
        yi[r >> 1][r & 1] = y_ws[(node0 + ia) * 128 + d];
        zi[r >> 1][r & 1] = s_xyz[ia * 4] * w0 + s_xyz[ia * 4 + 1] * w1c
                          + s_xyz[ia * 4 + 2] * w2c;
        a1[r >> 1][r & 1] = 0.f;
        a2[r >> 1][r & 1] = 0.f;
    }

    const float* yrow = y_ws + (node0 + h * 64) * 128 + d;
    const float* wp = s_w + h * 64 * 8;
    const float* xp = s_xyz + h * 64 * 4;

#pragma unroll 4
    for (int j = 0; j < 64; ++j) {
        const float yj = yrow[j * 128];
        floatx4 xj = *(const floatx4*)(xp + j * 4);         // broadcast
        const float zj = xj[0] * w0 + xj[1] * w1c + xj[2] * w2c;
        floatx4 wa = *(const floatx4*)(wp + j * 8);         // broadcast
        floatx4 wb = *(const floatx4*)(wp + j * 8 + 4);     // broadcast
        const floatx2 yj2 = {yj, yj}, zj2 = {zj, zj};
        floatx2 wlo = {wa[0], wa[1]}, wmd = {wa[2], wa[3]};
        floatx2 wh0 = {wb[0], wb[1]}, wh1 = {wb[2], wb[3]};
        a1[0] += __builtin_elementwise_max(wlo * (yi[0] - yj2) + b1v, zv2);
        a1[1] += __builtin_elementwise_max(wmd * (yi[1] - yj2) + b1v, zv2);
        a1[2] += __builtin_elementwise_max(wh0 * (yi[2] - yj2) + b1v, zv2);
        a1[3] += __builtin_elementwise_max(wh1 * (yi[3] - yj2) + b1v, zv2);
        a2[0] += __builtin_elementwise_max(zi[0] - zj2, zv2);
        a2[1] += __builtin_elementwise_max(zi[1] - zj2, zv2);
        a2[2] += __builtin_elementwise_max(zi[2] - zj2, zv2);
        a2[3] += __builtin_elementwise_max(zi[3] - zj2, zv2);
    }
    __syncthreads();   // s_w / s_xyz reads done

    // h=1 publishes partials
    if (h == 1) {
#pragma unroll
        for (int r = 0; r < 8; ++r) {
            s_red[r * 128 + d]        = a1[r >> 1][r & 1];
            s_red[1024 + r * 128 + d] = a2[r >> 1][r & 1];
        }
    }
    __syncthreads();

    // h=0 merges, subtracts p1 self term (w=1, diff=0 -> relu(b1d); p2 self = 0)
    if (h == 0) {
        const float selfc = fmaxf(b1d, 0.f);
        float bs = 0.f, bq = 0.f;
#pragma unroll
        for (int r = 0; r < 8; ++r) {
            float v1 = a1[r >> 1][r & 1] + s_red[r * 128 + d] - selfc;
            float v2 = a2[r >> 1][r & 1] + s_red[1024 + r * 128 + d];
            a1[r >> 1][r & 1] = v1;
            a2[r >> 1][r & 1] = v2;
            s_p1[r * 136 + d] = v1;
            bs += v2;
            bq += v2 * v2;
        }
        s_bn[d] = bs;
        s_bn[128 + d] = bq;
    }
    __syncthreads();

    // LN stats: 32 threads per i (8 i's x 32 = 256), 4 d's each, shuffle reduce
    {
        const int ii = tid >> 5, sub = tid & 31;
        floatx4 v = *(const floatx4*)(s_p1 + ii * 136 + sub * 4);
        float ps = v[0] + v[1] + v[2] + v[3];
        float pq = v[0] * v[0] + v[1] * v[1] + v[2] * v[2] + v[3] * v[3];
#pragma unroll
        for (int m = 1; m < 32; m <<= 1) {
            ps += __shfl_xor(ps, m, 64);
            pq += __shfl_xor(pq, m, 64);
        }
        if (sub == 0) {
            float mu = ps * (1.f / 128.f);
            float var = pq * (1.f / 128.f) - mu * mu;
            s_mu[ii] = mu;
            s_rs[ii] = rsqrtf(var + EPS);
        }
    }
    // BN partials -> 4 atomic banks
    if (tid < 128) {
        const int bank = (s & 3) * 256;
        atomicAdd(stat_ws + bank + d,       s_bn[d]);
        atomicAdd(stat_ws + bank + 128 + d, s_bn[128 + d]);
    }
    __syncthreads();

    // epilogue (h=0 holds the merged values): out = x + LN(p1)*lng + lnb ; store p2
    if (h == 0) {
        const float lng = ln_gamma[d], lnb = ln_beta[d];
#pragma unroll
        for (int r = 0; r < 8; ++r) {
            const int gi = node0 + i0 + r;
            float o = x[gi * 128 + d] + (a1[r >> 1][r & 1] - s_mu[r]) * s_rs[r] * lng + lnb;
            out[gi * 128 + d] = o;
            p2_ws[gi * 128 + d] = a2[r >> 1][r & 1];
        }
    }
}

// ---------------- finalize: out += BN(p2) ----------------
__global__ __launch_bounds__(256) void finalize_kernel(
    const float* __restrict__ p2_ws, const float* __restrict__ stat_ws,
    const float* __restrict__ bn_gamma, const float* __restrict__ bn_beta,
    float* __restrict__ out)
{
    __shared__ float sA[128], sB[128];
    const int tid = threadIdx.x;
    if (tid < 128) {
        float sm = 0.f, sq = 0.f;
#pragma unroll
        for (int b = 0; b < 4; ++b) {
            sm += stat_ws[b * 256 + tid];
            sq += stat_ws[b * 256 + 128 + tid];
        }
        float mu = sm * (1.f / 8192.f);
        float var = sq * (1.f / 8192.f) - mu * mu;
        float rs = rsqrtf(var + EPS);
        float A = rs * bn_gamma[tid];
        sA[tid] = A;
        sB[tid] = bn_beta[tid] - mu * A;
    }
    __syncthreads();
    const int base = (blockIdx.x * 256 + tid) * 4;
    const int d0 = base & 127;
    floatx4 p2 = *(const floatx4*)(p2_ws + base);
    floatx4 o  = *(const floatx4*)(out + base);
#pragma unroll
    for (int e = 0; e < 4; ++e)
        o[e] += p2[e] * sA[d0 + e] + sB[d0 + e];
    *(floatx4*)(out + base) = o;
}

extern "C" void kernel_launch(void* const* d_in, const int* in_sizes, int n_in,
                              void* d_out, int out_size, void* d_ws, size_t ws_size,
                              hipStream_t stream) {
    const float* x        = (const float*)d_in[0];
    const float* xyz      = (const float*)d_in[1];
    const float* W_xyz    = (const float*)d_in[2];
    const float* bn_gamma = (const float*)d_in[3];
    const float* bn_beta  = (const float*)d_in[4];
    const float* W1       = (const float*)d_in[5];
    const float* b1       = (const float*)d_in[6];
    const float* ln_gamma = (const float*)d_in[7];
    const float* ln_beta  = (const float*)d_in[8];
    float* out = (float*)d_out;

    float* y_ws    = (float*)d_ws;                       // [8192][128] fp32, 4 MB
    float* p2_ws   = y_ws + N_NODES * 128;               // [8192][128] fp32, 4 MB
    float* stat_ws = p2_ws + N_NODES * 128;              // 4 banks x (sum[128], sumsq[128])
    unsigned short* xb  = (unsigned short*)(stat_ws + 1024);  // [8192][128] bf16, 2 MB
    unsigned short* w1t = xb + N_NODES * 128;                 // [128][128] bf16 (transposed)

    prep_kernel<<<1040, 256, 0, stream>>>(x, W1, xb, w1t, stat_ws);
    gemm_y_kernel<<<512, 64, 0, stream>>>(xb, w1t, y_ws);
    cloud_main_kernel<<<1024, 256, 0, stream>>>(x, xyz, W_xyz, b1, ln_gamma, ln_beta,
                                                y_ws, p2_ws, stat_ws, out);
    finalize_kernel<<<1024, 256, 0, stream>>>(p2_ws, stat_ws, bn_gamma, bn_beta, out);
}